// Round 4
// baseline (249.464 us; speedup 1.0000x reference)
//
#include <hip/hip_runtime.h>
#include <hip/hip_bf16.h>

// AtomPoolingLayer: M=512 molecules, N=128 atoms, F=512 features, HID=128.
// Inputs fp32, OUTPUT fp32. out[m,f] = sum_n sigmoid(relu(h@W1+b1)@W2+b2)*h
//
// R3: passed at 77 us but latency-bound (Occupancy 19.5%, VALUBusy 8%,
// HBM 1.7/6.3 TB/s, FETCH already minimal at 134 MB). Fix: 512-thread
// blocks -> 16 waves/CU (was 8), 1 atom-strip per wave in phase 1
// (acc 64->32 VGPRs), explicit A-operand prefetch rotation.

typedef unsigned short u16;
typedef unsigned int u32;
typedef __bf16 bf16x8 __attribute__((ext_vector_type(8)));
typedef float f32x4 __attribute__((ext_vector_type(4)));
typedef u32 u32x4 __attribute__((ext_vector_type(4)));

#define M_MOL 512
#define N_ATOM 128
#define F_DIM 512
#define HID_DIM 128

static __device__ __forceinline__ u16 f2bf(float x) {
  u32 u = __float_as_uint(x);
  u32 r = (u + 0x7fffu + ((u >> 16) & 1u)) >> 16;  // RNE
  return (u16)r;
}
static __device__ __forceinline__ bf16x8 load8bf(const u16* p) {
  u32x4 v = *(const u32x4*)p;
  return __builtin_bit_cast(bf16x8, v);
}
// repack two fp32x4 -> bf16x8 by truncation (|rel err| <= 2^-8)
static __device__ __forceinline__ bf16x8 pack8(u32x4 a, u32x4 b) {
  u32x4 r;
  r[0] = (a[0] >> 16) | (a[1] & 0xffff0000u);
  r[1] = (a[2] >> 16) | (a[3] & 0xffff0000u);
  r[2] = (b[0] >> 16) | (b[1] & 0xffff0000u);
  r[3] = (b[2] >> 16) | (b[3] & 0xffff0000u);
  return __builtin_bit_cast(bf16x8, r);
}

// ---- Kernel 1: W1 fp32 [F=512][HID=128] -> W1T bf16 [HID=128][F=512] ----
__global__ __launch_bounds__(256) void transpose_w1(const float* __restrict__ W1,
                                                    u16* __restrict__ W1T) {
  __shared__ float tile[64][65];
  const int k0 = blockIdx.x * 64;
  const int n0 = blockIdx.y * 64;
  const int t = threadIdx.x;
  #pragma unroll
  for (int i = 0; i < 16; ++i) {
    const int lin = i * 256 + t;
    const int lr = lin >> 6, lc = lin & 63;
    tile[lc][lr] = W1[(size_t)(k0 + lr) * HID_DIM + (n0 + lc)];
  }
  __syncthreads();
  #pragma unroll
  for (int i = 0; i < 16; ++i) {
    const int lin = i * 256 + t;
    const int wr = lin >> 6, wc = lin & 63;
    W1T[(size_t)(n0 + wr) * F_DIM + (k0 + wc)] = f2bf(tile[wr][wc]);
  }
}

// ---- Kernel 2: fused gate + pooling; 512 threads (8 waves) per molecule ----
__global__ __launch_bounds__(512, 4) void atom_pool_kernel(
    const float* __restrict__ h, const u16* __restrict__ W1T,
    const float* __restrict__ b1, const float* __restrict__ W2,
    const float* __restrict__ b2, float* __restrict__ out) {
  const int m = blockIdx.x;
  const int tid = threadIdx.x;
  const int wv = tid >> 6;       // wave 0..7  -> atom strip wv*16..wv*16+15
  const int lane = tid & 63;
  const int quad = lane >> 4;    // 0..3
  const int cl = lane & 15;      // 0..15

  __shared__ float w_s[N_ATOM];        // gate weights per atom
  __shared__ float red[8][F_DIM];      // cross-wave reduction buffer (16 KB)

  const float* hm = h + (size_t)m * N_ATOM * F_DIM;

  // ===== Phase 1: T[atom][hid] = h[m] @ W1; MFMA 16x16x32 bf16 =====
  // A-frag: A[m=cl][k=quad*8+j]  (fp32 load + truncate-pack)
  // B-frag: B[k=quad*8+j][n=cl]  (W1T row, contiguous 16B)
  // C: row(atom)=quad*4+reg, col(hid)=cl
  f32x4 acc[8];
  #pragma unroll
  for (int t = 0; t < 8; ++t) acc[t] = (f32x4){0.f, 0.f, 0.f, 0.f};

  const float* arow = hm + (size_t)(wv * 16 + cl) * F_DIM;
  const int kb = quad * 8;

  // software-pipelined A prefetch: loads for iter ks+1 issue before MFMAs of ks
  u32x4 a_lo = *(const u32x4*)(arow + kb);
  u32x4 a_hi = *(const u32x4*)(arow + kb + 4);
  #pragma unroll 2
  for (int ks = 0; ks < 16; ++ks) {
    const int k = ks * 32 + kb;
    bf16x8 afr = pack8(a_lo, a_hi);
    if (ks < 15) {
      a_lo = *(const u32x4*)(arow + k + 32);
      a_hi = *(const u32x4*)(arow + k + 36);
    }
    #pragma unroll
    for (int t = 0; t < 8; ++t) {
      bf16x8 bfr = load8bf(W1T + (size_t)(t * 16 + cl) * F_DIM + k);
      acc[t] = __builtin_amdgcn_mfma_f32_16x16x32_bf16(afr, bfr, acc[t], 0, 0, 0);
    }
  }

  // Epilogue: relu(T + b1) @ W2, sigmoid -> w_s[atom]
  float psum[4] = {0.f, 0.f, 0.f, 0.f};
  #pragma unroll
  for (int t = 0; t < 8; ++t) {
    const int hid = t * 16 + cl;
    const float b1v = b1[hid];
    const float w2v = W2[hid];
    #pragma unroll
    for (int r = 0; r < 4; ++r) {
      float tv = fmaxf(acc[t][r] + b1v, 0.f);
      psum[r] = fmaf(tv, w2v, psum[r]);
    }
  }
  #pragma unroll
  for (int off = 1; off < 16; off <<= 1)
    #pragma unroll
    for (int r = 0; r < 4; ++r)
      psum[r] += __shfl_xor(psum[r], off, 64);
  if (cl == 0) {
    const float b2v = b2[0];
    #pragma unroll
    for (int r = 0; r < 4; ++r) {
      const int atom = wv * 16 + quad * 4 + r;
      w_s[atom] = 1.f / (1.f + __expf(-(psum[r] + b2v)));
    }
  }
  __syncthreads();

  // ===== Phase 2: out[m][f] = sum_n w_s[n] * h[m][n][f] (fp32, L2-warm) =====
  float facc[8] = {0.f, 0.f, 0.f, 0.f, 0.f, 0.f, 0.f, 0.f};
  const int f0 = lane * 8;                       // lane owns 8 features
  const float* hrow = hm + (size_t)(wv * 16) * F_DIM + f0;  // wave owns 16 atoms
  #pragma unroll 4
  for (int i = 0; i < 16; ++i) {
    const float wn = w_s[wv * 16 + i];
    f32x4 h0 = *(const f32x4*)(hrow + (size_t)i * F_DIM);
    f32x4 h1 = *(const f32x4*)(hrow + (size_t)i * F_DIM + 4);
    #pragma unroll
    for (int j = 0; j < 4; ++j) {
      facc[j]     = fmaf(wn, h0[j], facc[j]);
      facc[j + 4] = fmaf(wn, h1[j], facc[j + 4]);
    }
  }
  #pragma unroll
  for (int j = 0; j < 8; ++j) red[wv][f0 + j] = facc[j];
  __syncthreads();

  {
    const int f = tid;  // 512 threads x 1 feature
    float o = 0.f;
    #pragma unroll
    for (int k = 0; k < 8; ++k) o += red[k][f];
    out[(size_t)m * F_DIM + f] = o;
  }
}

extern "C" void kernel_launch(void* const* d_in, const int* in_sizes, int n_in,
                              void* d_out, int out_size, void* d_ws, size_t ws_size,
                              hipStream_t stream) {
  const float* h  = (const float*)d_in[0];   // [512,128,512] fp32
  const float* W1 = (const float*)d_in[1];   // [512,128] fp32
  const float* b1 = (const float*)d_in[2];   // [128] fp32
  const float* W2 = (const float*)d_in[3];   // [128,1] fp32
  const float* b2 = (const float*)d_in[4];   // [1] fp32
  float* out = (float*)d_out;                // [512,512] fp32
  u16* W1T = (u16*)d_ws;                     // 128 KiB scratch

  transpose_w1<<<dim3(8, 2), 256, 0, stream>>>(W1, W1T);
  atom_pool_kernel<<<M_MOL, 512, 0, stream>>>(h, W1T, b1, W2, b2, out);
}

// Round 5
// 223.562 us; speedup vs baseline: 1.1159x; 1.1159x over previous
//
#include <hip/hip_runtime.h>
#include <hip/hip_bf16.h>

// AtomPoolingLayer: M=512, N=128 atoms, F=512, HID=128. fp32 in, fp32 out.
// out[m,f] = sum_n sigmoid(relu(h[m,n,:]@W1+b1)@W2+b2) * h[m,n,f]
//
// R4 lesson: limiter = per-CU L1 line-miss concurrency (scattered 16-line
// fragment loads), NOT occupancy alone. R5: W1T k-tiles staged in LDS
// (register-prefetch pipeline), 64-atom blocks (grid 1024 -> 4 blocks/CU,
// 16 waves/CU), partial outputs reduced by a third tiny kernel.

typedef unsigned short u16;
typedef unsigned int u32;
typedef __bf16 bf16x8 __attribute__((ext_vector_type(8)));
typedef float f32x4 __attribute__((ext_vector_type(4)));
typedef float f32x2 __attribute__((ext_vector_type(2)));
typedef u32 u32x4 __attribute__((ext_vector_type(4)));

#define M_MOL 512
#define N_ATOM 128
#define F_DIM 512
#define HID_DIM 128
#define ABLK 64            // atoms per block
#define NBLK (M_MOL * 2)   // 1024 partial blocks

static __device__ __forceinline__ u16 f2bf(float x) {
  u32 u = __float_as_uint(x);
  u32 r = (u + 0x7fffu + ((u >> 16) & 1u)) >> 16;  // RNE
  return (u16)r;
}
// repack two fp32x4 -> bf16x8 by truncation (|rel err| <= 2^-8)
static __device__ __forceinline__ bf16x8 pack8(u32x4 a, u32x4 b) {
  u32x4 r;
  r[0] = (a[0] >> 16) | (a[1] & 0xffff0000u);
  r[1] = (a[2] >> 16) | (a[3] & 0xffff0000u);
  r[2] = (b[0] >> 16) | (b[1] & 0xffff0000u);
  r[3] = (b[2] >> 16) | (b[3] & 0xffff0000u);
  return __builtin_bit_cast(bf16x8, r);
}

// ---- Kernel 1: W1 fp32 [F=512][HID=128] -> W1T bf16 [HID=128][F=512] ----
__global__ __launch_bounds__(256) void transpose_w1(const float* __restrict__ W1,
                                                    u16* __restrict__ W1T) {
  __shared__ float tile[64][65];
  const int k0 = blockIdx.x * 64;
  const int n0 = blockIdx.y * 64;
  const int t = threadIdx.x;
  #pragma unroll
  for (int i = 0; i < 16; ++i) {
    const int lin = i * 256 + t;
    const int lr = lin >> 6, lc = lin & 63;
    tile[lc][lr] = W1[(size_t)(k0 + lr) * HID_DIM + (n0 + lc)];
  }
  __syncthreads();
  #pragma unroll
  for (int i = 0; i < 16; ++i) {
    const int lin = i * 256 + t;
    const int wr = lin >> 6, wc = lin & 63;
    W1T[(size_t)(n0 + wr) * F_DIM + (k0 + wc)] = f2bf(tile[wr][wc]);
  }
}

// ---- Kernel 2: 64-atom partial pooling; 256 threads (4 waves) ----
__global__ __launch_bounds__(256, 4) void pool_partial(
    const float* __restrict__ h, const u16* __restrict__ W1T,
    const float* __restrict__ b1, const float* __restrict__ W2,
    const float* __restrict__ b2, float* __restrict__ part) {
  __shared__ union SM {
    u16 bt[HID_DIM * 32];     // 8 KiB: B k-tile, [hid] rows of 32 k-elems
    float red[4][F_DIM];      // 8 KiB: phase-2 cross-wave reduce (after GEMM)
  } sm;
  __shared__ float w_s[ABLK];

  const int blk = blockIdx.x;
  const int tid = threadIdx.x;
  const int wv = tid >> 6;     // wave 0..3 -> atoms wv*16..+15
  const int lane = tid & 63;
  const int quad = lane >> 4;
  const int cl = lane & 15;

  const float* hb = h + (size_t)blk * ABLK * F_DIM;

  // A operand: wave's strip row, quad k-offset
  const float* arow = hb + (size_t)(wv * 16 + cl) * F_DIM;
  const int kb = quad * 8;

  // B staging: thread covers 32 B of the 8-KiB tile (row = tid/2, half = tid&1)
  const int srow = tid >> 1;
  const int scol = (tid & 1) * 16;  // elems
  const u16* sg = W1T + (size_t)srow * F_DIM + scol;
  u16* sl = sm.bt + srow * 32 + scol;

  f32x4 acc[8];
  #pragma unroll
  for (int t = 0; t < 8; ++t) acc[t] = (f32x4){0.f, 0.f, 0.f, 0.f};

  // prefetch tile ks=0 (B into regs) and A k-slice 0
  u32x4 st0 = *(const u32x4*)sg;
  u32x4 st1 = *(const u32x4*)(sg + 8);
  u32x4 a_lo = *(const u32x4*)(arow + kb);
  u32x4 a_hi = *(const u32x4*)(arow + kb + 4);

  #pragma unroll 2
  for (int ks = 0; ks < 16; ++ks) {
    __syncthreads();             // previous tile fully consumed
    *(u32x4*)sl = st0;           // regs -> LDS (2 x ds_write_b128)
    *(u32x4*)(sl + 8) = st1;
    __syncthreads();             // tile ready
    if (ks < 15) {               // prefetch next B tile into regs (L2-hot)
      st0 = *(const u32x4*)(sg + (ks + 1) * 32);
      st1 = *(const u32x4*)(sg + (ks + 1) * 32 + 8);
    }
    bf16x8 afr = pack8(a_lo, a_hi);
    if (ks < 15) {               // prefetch next A slice
      a_lo = *(const u32x4*)(arow + (ks + 1) * 32 + kb);
      a_hi = *(const u32x4*)(arow + (ks + 1) * 32 + kb + 4);
    }
    #pragma unroll
    for (int t = 0; t < 8; ++t) {
      bf16x8 bfr = *(const bf16x8*)(sm.bt + (t * 16 + cl) * 32 + kb);  // ds_read_b128
      acc[t] = __builtin_amdgcn_mfma_f32_16x16x32_bf16(afr, bfr, acc[t], 0, 0, 0);
    }
  }

  // Epilogue: w[atom] = sigmoid(relu(T+b1)@W2 + b2)
  float psum[4] = {0.f, 0.f, 0.f, 0.f};
  #pragma unroll
  for (int t = 0; t < 8; ++t) {
    const int hid = t * 16 + cl;
    const float b1v = b1[hid];
    const float w2v = W2[hid];
    #pragma unroll
    for (int r = 0; r < 4; ++r) {
      float tv = fmaxf(acc[t][r] + b1v, 0.f);
      psum[r] = fmaf(tv, w2v, psum[r]);
    }
  }
  #pragma unroll
  for (int off = 1; off < 16; off <<= 1)
    #pragma unroll
    for (int r = 0; r < 4; ++r)
      psum[r] += __shfl_xor(psum[r], off, 64);
  if (cl == 0) {
    const float b2v = b2[0];
    #pragma unroll
    for (int r = 0; r < 4; ++r)
      w_s[wv * 16 + quad * 4 + r] = 1.f / (1.f + __expf(-(psum[r] + b2v)));
  }
  __syncthreads();  // w_s ready; also: all waves done reading sm.bt

  // Phase 2: partial[f] = sum over this block's 64 atoms of w*h (h L2-warm)
  float facc[8] = {0.f, 0.f, 0.f, 0.f, 0.f, 0.f, 0.f, 0.f};
  const int f0 = lane * 8;
  const float* hrow = hb + (size_t)(wv * 16) * F_DIM + f0;
  #pragma unroll 4
  for (int i = 0; i < 16; ++i) {
    const float wn = w_s[wv * 16 + i];
    f32x4 h0 = *(const f32x4*)(hrow + (size_t)i * F_DIM);
    f32x4 h1 = *(const f32x4*)(hrow + (size_t)i * F_DIM + 4);
    #pragma unroll
    for (int j = 0; j < 4; ++j) {
      facc[j]     = fmaf(wn, h0[j], facc[j]);
      facc[j + 4] = fmaf(wn, h1[j], facc[j + 4]);
    }
  }
  #pragma unroll
  for (int j = 0; j < 8; ++j) sm.red[wv][f0 + j] = facc[j];
  __syncthreads();

  {
    const int f = tid * 2;
    f32x2 o;
    o[0] = sm.red[0][f] + sm.red[1][f] + sm.red[2][f] + sm.red[3][f];
    o[1] = sm.red[0][f + 1] + sm.red[1][f + 1] + sm.red[2][f + 1] + sm.red[3][f + 1];
    *(f32x2*)(part + (size_t)blk * F_DIM + f) = o;
  }
}

// ---- Kernel 3: out[m] = part[2m] + part[2m+1] ----
__global__ __launch_bounds__(256) void reduce_out(const float* __restrict__ part,
                                                  float* __restrict__ out) {
  const int m = blockIdx.x;
  const int f = threadIdx.x * 2;
  f32x2 a = *(const f32x2*)(part + (size_t)(2 * m) * F_DIM + f);
  f32x2 b = *(const f32x2*)(part + (size_t)(2 * m + 1) * F_DIM + f);
  f32x2 o;
  o[0] = a[0] + b[0];
  o[1] = a[1] + b[1];
  *(f32x2*)(out + (size_t)m * F_DIM + f) = o;
}

extern "C" void kernel_launch(void* const* d_in, const int* in_sizes, int n_in,
                              void* d_out, int out_size, void* d_ws, size_t ws_size,
                              hipStream_t stream) {
  const float* h  = (const float*)d_in[0];   // [512,128,512] fp32
  const float* W1 = (const float*)d_in[1];   // [512,128] fp32
  const float* b1 = (const float*)d_in[2];   // [128] fp32
  const float* W2 = (const float*)d_in[3];   // [128,1] fp32
  const float* b2 = (const float*)d_in[4];   // [1] fp32
  float* out = (float*)d_out;                // [512,512] fp32

  u16* W1T = (u16*)d_ws;                                  // 128 KiB
  float* part = (float*)((char*)d_ws + HID_DIM * F_DIM * sizeof(u16));  // 2 MiB

  transpose_w1<<<dim3(8, 2), 256, 0, stream>>>(W1, W1T);
  pool_partial<<<NBLK, 256, 0, stream>>>(h, W1T, b1, W2, b2, part);
  reduce_out<<<M_MOL, 256, 0, stream>>>(part, out);
}

// Round 6
// 214.146 us; speedup vs baseline: 1.1649x; 1.0440x over previous
//
#include <hip/hip_runtime.h>
#include <hip/hip_bf16.h>

// AtomPoolingLayer: M=512, N=128 atoms, F=512, HID=128. fp32 in, fp32 out.
// out[m,f] = sum_n sigmoid(relu(h[m,n,:]@W1+b1)@W2+b2) * h[m,n,f]
//
// R5 lesson: limiter = scattered vmem transactions + LDS bank conflicts
// (3.1e7 conflict-cycles!). R6: h-tile staged in LDS bf16 via fully
// coalesced loads w/ XOR-swizzled chunks (conflict-free reads for MFMA
// frags AND phase-2), W1T re-laid k-tile-contiguous for coalesced B
// staging, double-buffered B tiles. h touches HBM exactly once, every
// global access is a contiguous 1-KiB wave transaction.

typedef unsigned short u16;
typedef unsigned int u32;
typedef __bf16 bf16x8 __attribute__((ext_vector_type(8)));
typedef float f32x4 __attribute__((ext_vector_type(4)));
typedef float f32x2 __attribute__((ext_vector_type(2)));
typedef u32 u32x4 __attribute__((ext_vector_type(4)));

#define M_MOL 512
#define N_ATOM 128
#define F_DIM 512
#define HID_DIM 128
#define ABLK 64            // atoms per block
#define NBLK (M_MOL * 2)   // 1024 blocks

static __device__ __forceinline__ u16 f2bf(float x) {
  u32 u = __float_as_uint(x);
  u32 r = (u + 0x7fffu + ((u >> 16) & 1u)) >> 16;  // RNE
  return (u16)r;
}
// repack two fp32x4 -> bf16x8 by truncation (|rel err| <= 2^-8)
static __device__ __forceinline__ bf16x8 pack8(u32x4 a, u32x4 b) {
  u32x4 r;
  r[0] = (a[0] >> 16) | (a[1] & 0xffff0000u);
  r[1] = (a[2] >> 16) | (a[3] & 0xffff0000u);
  r[2] = (b[0] >> 16) | (b[1] & 0xffff0000u);
  r[3] = (b[2] >> 16) | (b[3] & 0xffff0000u);
  return __builtin_bit_cast(bf16x8, r);
}

// ---- Kernel 1: W1 fp32 [F=512][HID=128] -> W1Tt bf16 [ks][hid][32] ----
// k-tile-contiguous: tile ks (32 k-elems x 128 hid = 8 KiB) is contiguous.
__global__ __launch_bounds__(256) void transpose_w1(const float* __restrict__ W1,
                                                    u16* __restrict__ W1Tt) {
  __shared__ float tile[64][65];
  const int k0 = blockIdx.x * 64;
  const int n0 = blockIdx.y * 64;
  const int t = threadIdx.x;
  #pragma unroll
  for (int i = 0; i < 16; ++i) {
    const int lin = i * 256 + t;
    const int lr = lin >> 6, lc = lin & 63;
    tile[lc][lr] = W1[(size_t)(k0 + lr) * HID_DIM + (n0 + lc)];
  }
  __syncthreads();
  #pragma unroll
  for (int i = 0; i < 16; ++i) {
    const int lin = i * 256 + t;
    const int wr = lin >> 6, wc = lin & 63;   // wr: hid idx, wc: k idx
    const int k = k0 + wc;
    W1Tt[(size_t)(k >> 5) * (HID_DIM * 32) + (size_t)(n0 + wr) * 32 + (k & 31)] =
        f2bf(tile[wr][wc]);
  }
}

// ---- Kernel 2: 64-atom partial pooling; 256 threads (4 waves) ----
__global__ __launch_bounds__(256, 2) void pool_partial(
    const float* __restrict__ h, const u16* __restrict__ W1Tt,
    const float* __restrict__ b1, const float* __restrict__ W2,
    const float* __restrict__ b2, float* __restrict__ part) {
  // As: h tile bf16, 64 rows x 512 elems; 16-B chunk c of row r stored at
  // chunk position (c&~7)|((c^r)&7)  -> conflict-free for all access modes.
  __shared__ u16 As[ABLK * F_DIM];          // 64 KiB
  __shared__ union U {
    u16 bt[2][HID_DIM * 32];                // 16 KiB: double-buffered B tiles
    struct {
      float w_s[ABLK];                      // offset 0     (inside bt[0])
      float _pad[2048 - ABLK];
      float red[4][F_DIM];                  // offset 8 KiB (inside bt[1])
    } s;
  } sm;

  const int blk = blockIdx.x;
  const int tid = threadIdx.x;
  const int wv = tid >> 6;     // wave 0..3 -> atoms wv*16..+15
  const int lane = tid & 63;
  const int quad = lane >> 4;
  const int cl = lane & 15;

  // ---- Stage A: 128 KiB fp32 -> 64 KiB bf16 LDS, fully coalesced ----
  {
    const u32x4* hg = (const u32x4*)(h + (size_t)blk * ABLK * F_DIM);
    #pragma unroll
    for (int i = 0; i < 16; ++i) {
      const int u = i * 256 + tid;          // 32-B fp32 unit index (0..4095)
      const int row = u >> 6;               // 64 units per 2-KiB row
      const int c = u & 63;                 // dest 16-B bf16 chunk in row
      u32x4 lo = hg[2 * u];
      u32x4 hi = hg[2 * u + 1];
      const int phys = (c & ~7) | ((c ^ row) & 7);
      *(bf16x8*)(As + row * F_DIM + phys * 8) = pack8(lo, hi);
    }
  }

  // ---- Stage B tile 0 (8 KiB coalesced from W1Tt) ----
  const u16* wg = W1Tt + tid * 16;          // thread's 32 B within a tile
  const int brow = tid >> 1;                // bt row (hid)
  const int bc0 = 2 * (tid & 1);            // first 16-B chunk (of 4 per row)
  u16* bw0 = sm.bt[0] + brow * 32;
  u16* bw1 = sm.bt[1] + brow * 32;
  const int bphysA = (bc0 ^ (brow & 3)) * 8;
  const int bphysB = ((bc0 + 1) ^ (brow & 3)) * 8;
  {
    u32x4 v0 = *(const u32x4*)wg;
    u32x4 v1 = *(const u32x4*)(wg + 8);
    *(u32x4*)(bw0 + bphysA) = v0;
    *(u32x4*)(bw0 + bphysB) = v1;
  }
  __syncthreads();

  // ---- Phase 1: T[atom][hid] = h @ W1, MFMA 16x16x32 bf16 ----
  f32x4 acc[8];
  #pragma unroll
  for (int t = 0; t < 8; ++t) acc[t] = (f32x4){0.f, 0.f, 0.f, 0.f};

  const int ar = wv * 16 + cl;              // A row (atom)
  const u16* aBase = As + ar * F_DIM;
  const int bq = (quad ^ (cl & 3)) * 8;     // B chunk offset (swizzled)

  for (int ks = 0; ks < 16; ++ks) {
    u32x4 v0, v1;
    if (ks < 15) {                          // prefetch next B tile (L2-hot)
      v0 = *(const u32x4*)(wg + (ks + 1) * (HID_DIM * 32));
      v1 = *(const u32x4*)(wg + (ks + 1) * (HID_DIM * 32) + 8);
    }
    // A fragment: chunk c = ks*4+quad of row ar
    const int c = ks * 4 + quad;
    const int aphys = (c & ~7) | ((c ^ ar) & 7);
    bf16x8 afr = *(const bf16x8*)(aBase + aphys * 8);
    const u16* btb = sm.bt[ks & 1];
    #pragma unroll
    for (int t = 0; t < 8; ++t) {
      bf16x8 bfr = *(const bf16x8*)(btb + (t * 16 + cl) * 32 + bq);
      acc[t] = __builtin_amdgcn_mfma_f32_16x16x32_bf16(afr, bfr, acc[t], 0, 0, 0);
    }
    if (ks < 15) {
      u16* bw = (ks & 1) ? bw0 : bw1;       // write buffer (ks+1)&1
      *(u32x4*)(bw + bphysA) = v0;
      *(u32x4*)(bw + bphysB) = v1;
      __syncthreads();
    }
  }

  // ---- Epilogue: w[atom] = sigmoid(relu(T+b1)@W2 + b2) ----
  float psum[4] = {0.f, 0.f, 0.f, 0.f};
  #pragma unroll
  for (int t = 0; t < 8; ++t) {
    const int hid = t * 16 + cl;
    const float b1v = b1[hid];
    const float w2v = W2[hid];
    #pragma unroll
    for (int r = 0; r < 4; ++r) {
      float tv = fmaxf(acc[t][r] + b1v, 0.f);
      psum[r] = fmaf(tv, w2v, psum[r]);
    }
  }
  #pragma unroll
  for (int off = 1; off < 16; off <<= 1)
    #pragma unroll
    for (int r = 0; r < 4; ++r)
      psum[r] += __shfl_xor(psum[r], off, 64);
  if (cl == 0) {
    const float b2v = b2[0];
    #pragma unroll
    for (int r = 0; r < 4; ++r)
      sm.s.w_s[wv * 16 + quad * 4 + r] = 1.f / (1.f + __expf(-(psum[r] + b2v)));
  }
  __syncthreads();   // w_s ready; all waves done with bt

  // ---- Phase 2: partial[f] = sum over 64 atoms of w * h, from LDS ----
  float facc[8] = {0.f, 0.f, 0.f, 0.f, 0.f, 0.f, 0.f, 0.f};
  #pragma unroll 4
  for (int i = 0; i < 16; ++i) {
    const int row = wv * 16 + i;
    const float wn = sm.s.w_s[row];
    const int phys = (lane & ~7) | ((lane ^ row) & 7);
    bf16x8 hv = *(const bf16x8*)(As + row * F_DIM + phys * 8);
    u32x4 uv = __builtin_bit_cast(u32x4, hv);
    #pragma unroll
    for (int j = 0; j < 4; ++j) {
      facc[2 * j]     = fmaf(wn, __uint_as_float(uv[j] << 16), facc[2 * j]);
      facc[2 * j + 1] = fmaf(wn, __uint_as_float(uv[j] & 0xffff0000u), facc[2 * j + 1]);
    }
  }
  #pragma unroll
  for (int j = 0; j < 8; ++j) sm.s.red[wv][lane * 8 + j] = facc[j];
  __syncthreads();

  {
    const int f = tid * 2;
    f32x2 o;
    o[0] = sm.s.red[0][f] + sm.s.red[1][f] + sm.s.red[2][f] + sm.s.red[3][f];
    o[1] = sm.s.red[0][f + 1] + sm.s.red[1][f + 1] + sm.s.red[2][f + 1] + sm.s.red[3][f + 1];
    *(f32x2*)(part + (size_t)blk * F_DIM + f) = o;
  }
}

// ---- Kernel 3: out[m] = part[2m] + part[2m+1] ----
__global__ __launch_bounds__(256) void reduce_out(const float* __restrict__ part,
                                                  float* __restrict__ out) {
  const int m = blockIdx.x;
  const int f = threadIdx.x * 2;
  f32x2 a = *(const f32x2*)(part + (size_t)(2 * m) * F_DIM + f);
  f32x2 b = *(const f32x2*)(part + (size_t)(2 * m + 1) * F_DIM + f);
  f32x2 o;
  o[0] = a[0] + b[0];
  o[1] = a[1] + b[1];
  *(f32x2*)(out + (size_t)m * F_DIM + f) = o;
}

extern "C" void kernel_launch(void* const* d_in, const int* in_sizes, int n_in,
                              void* d_out, int out_size, void* d_ws, size_t ws_size,
                              hipStream_t stream) {
  const float* h  = (const float*)d_in[0];   // [512,128,512] fp32
  const float* W1 = (const float*)d_in[1];   // [512,128] fp32
  const float* b1 = (const float*)d_in[2];   // [128] fp32
  const float* W2 = (const float*)d_in[3];   // [128,1] fp32
  const float* b2 = (const float*)d_in[4];   // [1] fp32
  float* out = (float*)d_out;                // [512,512] fp32

  u16* W1Tt = (u16*)d_ws;                                 // 128 KiB (tiled)
  float* part = (float*)((char*)d_ws + (size_t)HID_DIM * F_DIM * sizeof(u16));  // 2 MiB

  transpose_w1<<<dim3(8, 2), 256, 0, stream>>>(W1, W1Tt);
  pool_partial<<<NBLK, 256, 0, stream>>>(h, W1Tt, b1, W2, b2, part);
  reduce_out<<<M_MOL, 256, 0, stream>>>(part, out);
}